// Round 1
// baseline (481.309 us; speedup 1.0000x reference)
//
#include <hip/hip_runtime.h>
#include <hip/hip_bf16.h>

// Problem dims (fixed by the reference)
#define B 64
#define T 2048
#define H 512
#define S 512
#define K 128
#define V 128
#define SPLITS 16          // split-T factor for the weighted-reduce pass
#define TPS (T / SPLITS)   // 128 rows per split

// ---------------------------------------------------------------------------
// Kernel A: per-batch prep.
//   query[b,k] = dec[b,:]·Ws[k,:] + bs[k]
//   wq[b,h]    = sum_k query[b,k]*Wh[k,h]
//   c[b]       = sum_k query[b,k]*bh[k]
// grid = B, block = 256
// ---------------------------------------------------------------------------
__global__ __launch_bounds__(256) void prep_kernel(
    const float* __restrict__ dec, const float* __restrict__ Ws,
    const float* __restrict__ bs, const float* __restrict__ Wh,
    const float* __restrict__ bh, float* __restrict__ wq,
    float* __restrict__ cb) {
  const int b = blockIdx.x;
  const int tid = threadIdx.x;
  __shared__ float s_dec[S];
  __shared__ float s_q[K];

  for (int i = tid; i < S; i += 256) s_dec[i] = dec[b * S + i];
  __syncthreads();

  if (tid < K) {
    const float* w = Ws + (size_t)tid * S;
    float acc = bs[tid];
    #pragma unroll 4
    for (int s = 0; s < S; s++) acc += w[s] * s_dec[s];
    s_q[tid] = acc;
  }
  __syncthreads();

  if (tid == 0) {
    float c = 0.f;
    for (int k = 0; k < K; k++) c += s_q[k] * bh[k];
    cb[b] = c;
  }
  for (int h = tid; h < H; h += 256) {
    float acc = 0.f;
    #pragma unroll 4
    for (int k = 0; k < K; k++) acc += s_q[k] * Wh[(size_t)k * H + h];
    wq[b * H + h] = acc;
  }
}

// ---------------------------------------------------------------------------
// Kernel B: energy[b,t] = L[b,t,:]·wq[b,:] + c[b]   (streams listener once)
// grid = B * (T/32), block = 256 (4 waves, 8 rows/wave)
// ---------------------------------------------------------------------------
__global__ __launch_bounds__(256) void energy_kernel(
    const float* __restrict__ L, const float* __restrict__ wq,
    const float* __restrict__ cb, float* __restrict__ energy) {
  const int b = blockIdx.x >> 6;    // T/32 = 64 chunks per batch
  const int tc = blockIdx.x & 63;
  const int lane = threadIdx.x & 63;
  const int wave = threadIdx.x >> 6;

  const float4 q0 = *(const float4*)(wq + b * H + lane * 8);
  const float4 q1 = *(const float4*)(wq + b * H + lane * 8 + 4);
  const float c = cb[b];
  const float* Lb = L + (size_t)b * T * H;

  #pragma unroll
  for (int i = 0; i < 8; i++) {
    const int t = tc * 32 + wave * 8 + i;
    const float* row = Lb + (size_t)t * H + lane * 8;
    const float4 a0 = *(const float4*)(row);
    const float4 a1 = *(const float4*)(row + 4);
    float d = a0.x * q0.x + a0.y * q0.y + a0.z * q0.z + a0.w * q0.w +
              a1.x * q1.x + a1.y * q1.y + a1.z * q1.z + a1.w * q1.w;
    #pragma unroll
    for (int off = 32; off > 0; off >>= 1) d += __shfl_xor(d, off);
    if (lane == 0) energy[b * T + t] = d + c;
  }
}

// ---------------------------------------------------------------------------
// Kernel C: masked softmax + L1 renorm == masked softmax over valid set.
//   valid: t < len[b], except b==0 -> all valid.
// grid = B, block = 256 (8 t-positions per thread, coalesced stride-256)
// ---------------------------------------------------------------------------
__global__ __launch_bounds__(256) void softmax_kernel(
    const float* __restrict__ energy, const int* __restrict__ len,
    float* __restrict__ att) {
  const int b = blockIdx.x;
  const int tid = threadIdx.x;
  const int lane = tid & 63;
  const int wave = tid >> 6;
  const int lb = (b == 0) ? T : len[b];

  float e[8];
  bool v[8];
  float m = -1e30f;
  #pragma unroll
  for (int i = 0; i < 8; i++) {
    const int t = tid + 256 * i;
    e[i] = energy[b * T + t];
    v[i] = (t < lb);
    if (v[i]) m = fmaxf(m, e[i]);
  }
  #pragma unroll
  for (int off = 32; off > 0; off >>= 1) m = fmaxf(m, __shfl_xor(m, off));
  __shared__ float sm[4];
  __shared__ float sl[4];
  if (lane == 0) sm[wave] = m;
  __syncthreads();
  m = fmaxf(fmaxf(sm[0], sm[1]), fmaxf(sm[2], sm[3]));

  float w[8];
  float l = 0.f;
  #pragma unroll
  for (int i = 0; i < 8; i++) {
    w[i] = v[i] ? __expf(e[i] - m) : 0.f;
    l += w[i];
  }
  #pragma unroll
  for (int off = 32; off > 0; off >>= 1) l += __shfl_xor(l, off);
  if (lane == 0) sl[wave] = l;
  __syncthreads();
  l = sl[0] + sl[1] + sl[2] + sl[3];
  const float inv = 1.0f / fmaxf(l, 1e-12f);
  #pragma unroll
  for (int i = 0; i < 8; i++) att[b * T + tid + 256 * i] = w[i] * inv;
}

// ---------------------------------------------------------------------------
// Kernel D: partial ctx[b,h] = sum_{t in split} att[b,t]*L[b,t,h]
// grid = B*SPLITS, block = 256 (each thread owns 2 h-columns, float2)
// ---------------------------------------------------------------------------
__global__ __launch_bounds__(256) void ctx_partial_kernel(
    const float* __restrict__ L, const float* __restrict__ att,
    float* __restrict__ partials) {
  const int b = blockIdx.x >> 4;
  const int sp = blockIdx.x & (SPLITS - 1);
  const int tid = threadIdx.x;
  const int t0 = sp * TPS;

  __shared__ float s_w[TPS];
  for (int i = tid; i < TPS; i += 256) s_w[i] = att[b * T + t0 + i];
  __syncthreads();

  const float* Lp = L + (size_t)b * T * H + (size_t)t0 * H + tid * 2;
  float2 acc = {0.f, 0.f};
  #pragma unroll 4
  for (int t = 0; t < TPS; t++) {
    const float wv = s_w[t];
    const float2 x = *(const float2*)(Lp + (size_t)t * H);
    acc.x += wv * x.x;
    acc.y += wv * x.y;
  }
  *(float2*)(partials + ((size_t)(b * SPLITS + sp)) * H + tid * 2) = acc;
}

// ---------------------------------------------------------------------------
// Kernel E: combine splits, then context[b,v] = ctx[b,:]·Wv[v,:] + bv[v]
// grid = B, block = 256
// ---------------------------------------------------------------------------
__global__ __launch_bounds__(256) void finalize_kernel(
    const float* __restrict__ partials, const float* __restrict__ Wv,
    const float* __restrict__ bv, float* __restrict__ ctx_out) {
  const int b = blockIdx.x;
  const int tid = threadIdx.x;
  __shared__ float s_ctx[H];

  float2 acc = {0.f, 0.f};
  #pragma unroll
  for (int sp = 0; sp < SPLITS; sp++) {
    const float2 p =
        *(const float2*)(partials + ((size_t)(b * SPLITS + sp)) * H + tid * 2);
    acc.x += p.x;
    acc.y += p.y;
  }
  s_ctx[tid * 2] = acc.x;
  s_ctx[tid * 2 + 1] = acc.y;
  __syncthreads();

  if (tid < V) {
    const float* w = Wv + (size_t)tid * H;
    float a = bv[tid];
    #pragma unroll 4
    for (int h = 0; h < H; h += 4) {
      a += w[h] * s_ctx[h] + w[h + 1] * s_ctx[h + 1] + w[h + 2] * s_ctx[h + 2] +
           w[h + 3] * s_ctx[h + 3];
    }
    ctx_out[b * V + tid] = a;
  }
}

extern "C" void kernel_launch(void* const* d_in, const int* in_sizes, int n_in,
                              void* d_out, int out_size, void* d_ws,
                              size_t ws_size, hipStream_t stream) {
  const float* dec = (const float*)d_in[0];   // (B,S)
  const float* L   = (const float*)d_in[1];   // (B,T,H)
  const int*   len = (const int*)d_in[2];     // (B,)
  const float* Ws  = (const float*)d_in[3];   // (K,S)
  const float* bs  = (const float*)d_in[4];   // (K,)
  const float* Wh  = (const float*)d_in[5];   // (K,H)
  const float* bh  = (const float*)d_in[6];   // (K,)
  const float* Wv  = (const float*)d_in[7];   // (V,H)
  const float* bv  = (const float*)d_in[8];   // (V,)

  float* ctx_out = (float*)d_out;             // (B,V) = 8192 floats
  float* att_out = (float*)d_out + B * V;     // (B,1,T) = 131072 floats

  // workspace layout (floats): wq[B*H] | cb[B] | energy[B*T] | partials[B*SPLITS*H]
  float* ws = (float*)d_ws;
  float* wq = ws;                      // 32768
  float* cb = wq + B * H;              // 64
  float* energy = cb + B;              // 131072
  float* partials = energy + B * T;    // 524288   (total ~2.75 MB)

  prep_kernel<<<B, 256, 0, stream>>>(dec, Ws, bs, Wh, bh, wq, cb);
  energy_kernel<<<B * (T / 32), 256, 0, stream>>>(L, wq, cb, energy);
  softmax_kernel<<<B, 256, 0, stream>>>(energy, len, att_out);
  ctx_partial_kernel<<<B * SPLITS, 256, 0, stream>>>(L, att_out, partials);
  finalize_kernel<<<B, 256, 0, stream>>>(partials, Wv, bv, ctx_out);
}

// Round 2
// 421.697 us; speedup vs baseline: 1.1414x; 1.1414x over previous
//
#include <hip/hip_runtime.h>
#include <hip/hip_bf16.h>

// Problem dims (fixed by the reference)
#define B 64
#define T 2048
#define H 512
#define S 512
#define K 128
#define V 128
#define SPL 16           // splits over T for the fused pass
#define RPB (T / SPL)    // 128 rows per block
#define RPW (RPB / 4)    // 32 rows per wave (4 waves/block)
#define PSTRIDE 516      // per-block partial: 512 ctx + m + l (+2 pad)

// ---------------------------------------------------------------------------
// Kernel A: per-batch prep.
//   query[b,k] = dec[b,:]·Ws[k,:] + bs[k]
//   wq[b,h]    = sum_k query[b,k]*Wh[k,h]
//   c[b]       = sum_k query[b,k]*bh[k]
// ---------------------------------------------------------------------------
__global__ __launch_bounds__(256) void prep_kernel(
    const float* __restrict__ dec, const float* __restrict__ Ws,
    const float* __restrict__ bs, const float* __restrict__ Wh,
    const float* __restrict__ bh, float* __restrict__ wq,
    float* __restrict__ cb) {
  const int b = blockIdx.x;
  const int tid = threadIdx.x;
  __shared__ float s_dec[S];
  __shared__ float s_q[K];

  for (int i = tid; i < S; i += 256) s_dec[i] = dec[b * S + i];
  __syncthreads();

  if (tid < K) {
    const float* w = Ws + (size_t)tid * S;
    float acc = bs[tid];
    #pragma unroll 4
    for (int s = 0; s < S; s++) acc += w[s] * s_dec[s];
    s_q[tid] = acc;
  }
  __syncthreads();

  if (tid == 0) {
    float c = 0.f;
    for (int k = 0; k < K; k++) c += s_q[k] * bh[k];
    cb[b] = c;
  }
  for (int h = tid; h < H; h += 256) {
    float acc = 0.f;
    #pragma unroll 4
    for (int k = 0; k < K; k++) acc += s_q[k] * Wh[(size_t)k * H + h];
    wq[b * H + h] = acc;
  }
}

// ---------------------------------------------------------------------------
// Kernel B (fused): single pass over VALID rows of L.
// One wave per row: lane holds h = lane*4..+4 and 256+lane*4..+4.
//   e_t = L[t,:]·wq + c  (butterfly-reduced, wave-uniform)
//   online softmax: m,l running; acc[h] += exp(e-m)*L[t,h] with uniform rescale
// Invalid rows (t >= len, b!=0) are never loaded.
// Writes per-block partial: ctx[512], M, l.  Writes energy[t] for valid t.
// ---------------------------------------------------------------------------
__global__ __launch_bounds__(256) void fused_kernel(
    const float* __restrict__ L, const float* __restrict__ wq,
    const float* __restrict__ cb, const int* __restrict__ len,
    float* __restrict__ energy, float* __restrict__ partials) {
  const int b = blockIdx.x >> 4;
  const int sp = blockIdx.x & (SPL - 1);
  const int lane = threadIdx.x & 63;
  const int wave = threadIdx.x >> 6;
  const int tid = threadIdx.x;
  const int lb = (b == 0) ? T : len[b];

  __shared__ float s_ctx[4][H];
  __shared__ float s_ml[4][2];

  const int h0 = lane * 4;
  float m = -__builtin_huge_valf();
  float lsum = 0.f;
  float4 acc0 = {0.f, 0.f, 0.f, 0.f};
  float4 acc1 = {0.f, 0.f, 0.f, 0.f};

  const int start = sp * RPB + wave * RPW;
  const int end = min(start + RPW, lb);

  if (start < end) {
    const float4 q0 = *(const float4*)(wq + b * H + h0);
    const float4 q1 = *(const float4*)(wq + b * H + 256 + h0);
    const float c = cb[b];
    const float* Lr = L + ((size_t)b * T + start) * H;
    for (int r = start; r < end; r++, Lr += H) {
      const float4 a0 = *(const float4*)(Lr + h0);
      const float4 a1 = *(const float4*)(Lr + 256 + h0);
      float d = a0.x * q0.x + a0.y * q0.y + a0.z * q0.z + a0.w * q0.w +
                a1.x * q1.x + a1.y * q1.y + a1.z * q1.z + a1.w * q1.w;
      #pragma unroll
      for (int off = 32; off > 0; off >>= 1) d += __shfl_xor(d, off);
      const float e = d + c;   // wave-uniform
      if (lane == 0) energy[b * T + r] = e;
      if (e > m) {             // wave-uniform branch, rare after warm-up
        const float s = __expf(m - e);
        lsum *= s;
        acc0.x *= s; acc0.y *= s; acc0.z *= s; acc0.w *= s;
        acc1.x *= s; acc1.y *= s; acc1.z *= s; acc1.w *= s;
        m = e;
      }
      const float w = __expf(e - m);
      lsum += w;
      acc0.x += w * a0.x; acc0.y += w * a0.y;
      acc0.z += w * a0.z; acc0.w += w * a0.w;
      acc1.x += w * a1.x; acc1.y += w * a1.y;
      acc1.z += w * a1.z; acc1.w += w * a1.w;
    }
  }

  if (lane == 0) { s_ml[wave][0] = m; s_ml[wave][1] = lsum; }
  *(float4*)&s_ctx[wave][h0] = acc0;
  *(float4*)&s_ctx[wave][256 + h0] = acc1;
  __syncthreads();

  const float M = fmaxf(fmaxf(s_ml[0][0], s_ml[1][0]),
                        fmaxf(s_ml[2][0], s_ml[3][0]));
  float sc[4], ltot = 0.f;
  #pragma unroll
  for (int w = 0; w < 4; w++) {
    sc[w] = (s_ml[w][0] > -1e38f) ? __expf(s_ml[w][0] - M) : 0.f;
    ltot += s_ml[w][1] * sc[w];
  }
  float v0 = 0.f, v1 = 0.f;
  #pragma unroll
  for (int w = 0; w < 4; w++) {
    v0 += s_ctx[w][tid * 2] * sc[w];
    v1 += s_ctx[w][tid * 2 + 1] * sc[w];
  }
  float* part = partials + (size_t)blockIdx.x * PSTRIDE;
  *(float2*)(part + tid * 2) = make_float2(v0, v1);
  if (tid == 0) { part[512] = M; part[513] = ltot; }
}

// ---------------------------------------------------------------------------
// Kernel C: combine SPL split-partials per batch, then Wv GEMV.
// Also writes per-batch (M_global, 1/l_total) for the attention-write kernel.
// ---------------------------------------------------------------------------
__global__ __launch_bounds__(256) void combine_kernel(
    const float* __restrict__ partials, const float* __restrict__ Wv,
    const float* __restrict__ bv, float* __restrict__ ctx_out,
    float* __restrict__ Mv, float* __restrict__ Iv) {
  const int b = blockIdx.x;
  const int tid = threadIdx.x;
  __shared__ float s_ml[SPL][2];
  __shared__ float s_ctx[H];

  if (tid < SPL) {
    const float* p = partials + (size_t)(b * SPL + tid) * PSTRIDE;
    s_ml[tid][0] = p[512];
    s_ml[tid][1] = p[513];
  }
  __syncthreads();

  float M = -__builtin_huge_valf();
  #pragma unroll
  for (int sp = 0; sp < SPL; sp++) M = fmaxf(M, s_ml[sp][0]);
  float sc[SPL], ltot = 0.f;
  #pragma unroll
  for (int sp = 0; sp < SPL; sp++) {
    sc[sp] = (s_ml[sp][0] > -1e38f) ? __expf(s_ml[sp][0] - M) : 0.f;
    ltot += s_ml[sp][1] * sc[sp];
  }
  const float inv = 1.0f / fmaxf(ltot, 1e-12f);

  float v0 = 0.f, v1 = 0.f;
  #pragma unroll 4
  for (int sp = 0; sp < SPL; sp++) {
    const float* p = partials + (size_t)(b * SPL + sp) * PSTRIDE;
    v0 += p[tid * 2] * sc[sp];
    v1 += p[tid * 2 + 1] * sc[sp];
  }
  s_ctx[tid * 2] = v0 * inv;
  s_ctx[tid * 2 + 1] = v1 * inv;
  if (tid == 0) { Mv[b] = M; Iv[b] = inv; }
  __syncthreads();

  if (tid < V) {
    const float* w = Wv + (size_t)tid * H;
    float a = bv[tid];
    #pragma unroll 4
    for (int h = 0; h < H; h += 4) {
      a += w[h] * s_ctx[h] + w[h + 1] * s_ctx[h + 1] +
           w[h + 2] * s_ctx[h + 2] + w[h + 3] * s_ctx[h + 3];
    }
    ctx_out[b * V + tid] = a;
  }
}

// ---------------------------------------------------------------------------
// Kernel D: att[b,t] = (t < len) ? exp(e_t - M)*inv : 0
// ---------------------------------------------------------------------------
__global__ __launch_bounds__(256) void attwrite_kernel(
    const float* __restrict__ energy, const int* __restrict__ len,
    const float* __restrict__ Mv, const float* __restrict__ Iv,
    float* __restrict__ att) {
  const int b = blockIdx.x;
  const int tid = threadIdx.x;
  const int lb = (b == 0) ? T : len[b];
  const float M = Mv[b];
  const float inv = Iv[b];
  #pragma unroll
  for (int i = 0; i < 8; i++) {
    const int t = tid + 256 * i;
    const float e = (t < lb) ? energy[b * T + t] : M;  // avoid poison in expf
    att[b * T + t] = (t < lb) ? __expf(e - M) * inv : 0.f;
  }
}

extern "C" void kernel_launch(void* const* d_in, const int* in_sizes, int n_in,
                              void* d_out, int out_size, void* d_ws,
                              size_t ws_size, hipStream_t stream) {
  const float* dec = (const float*)d_in[0];   // (B,S)
  const float* L   = (const float*)d_in[1];   // (B,T,H)
  const int*   len = (const int*)d_in[2];     // (B,)
  const float* Ws  = (const float*)d_in[3];   // (K,S)
  const float* bs  = (const float*)d_in[4];   // (K,)
  const float* Wh  = (const float*)d_in[5];   // (K,H)
  const float* bh  = (const float*)d_in[6];   // (K,)
  const float* Wv  = (const float*)d_in[7];   // (V,H)
  const float* bv  = (const float*)d_in[8];   // (V,)

  float* ctx_out = (float*)d_out;             // (B,V)
  float* att_out = (float*)d_out + B * V;     // (B,1,T)

  // workspace layout (floats):
  float* ws = (float*)d_ws;
  float* wq = ws;                               // B*H      = 32768
  float* cb = wq + B * H;                       // B        = 64
  float* energy = cb + B;                       // B*T      = 131072
  float* partials = energy + B * T;             // B*SPL*PSTRIDE = 528384
  float* Mv = partials + B * SPL * PSTRIDE;     // B
  float* Iv = Mv + B;                           // B

  prep_kernel<<<B, 256, 0, stream>>>(dec, Ws, bs, Wh, bh, wq, cb);
  fused_kernel<<<B * SPL, 256, 0, stream>>>(L, wq, cb, len, energy, partials);
  combine_kernel<<<B, 256, 0, stream>>>(partials, Wv, bv, ctx_out, Mv, Iv);
  attwrite_kernel<<<B, 256, 0, stream>>>(energy, len, Mv, Iv, att_out);
}

// Round 3
// 416.046 us; speedup vs baseline: 1.1569x; 1.0136x over previous
//
#include <hip/hip_runtime.h>
#include <hip/hip_bf16.h>

// Problem dims (fixed by the reference)
#define B 64
#define T 2048
#define H 512
#define S 512
#define K 128
#define V 128
#define SPL 32           // splits over T for the fused pass (finer -> better balance)
#define RPB (T / SPL)    // 64 rows per block
#define RPW (RPB / 4)    // 16 rows per wave (4 waves/block)
#define PSTRIDE 516      // per-block partial: 512 ctx + m + l (+2 pad)

// ---------------------------------------------------------------------------
// Kernel A: per-batch prep.
//   query[b,k] = dec[b,:]·Ws[k,:] + bs[k]
//   wq[b,h]    = sum_k query[b,k]*Wh[k,h]
//   c[b]       = sum_k query[b,k]*bh[k]
// ---------------------------------------------------------------------------
__global__ __launch_bounds__(256) void prep_kernel(
    const float* __restrict__ dec, const float* __restrict__ Ws,
    const float* __restrict__ bs, const float* __restrict__ Wh,
    const float* __restrict__ bh, float* __restrict__ wq,
    float* __restrict__ cb) {
  const int b = blockIdx.x;
  const int tid = threadIdx.x;
  __shared__ float s_dec[S];
  __shared__ float s_q[K];

  for (int i = tid; i < S; i += 256) s_dec[i] = dec[b * S + i];
  __syncthreads();

  if (tid < K) {
    const float* w = Ws + (size_t)tid * S;
    float acc = bs[tid];
    #pragma unroll 4
    for (int s = 0; s < S; s += 4) {
      const float4 wv = *(const float4*)(w + s);
      const float4 dv = *(const float4*)(s_dec + s);
      acc += wv.x * dv.x + wv.y * dv.y + wv.z * dv.z + wv.w * dv.w;
    }
    s_q[tid] = acc;
  }
  __syncthreads();

  if (tid == 0) {
    float c = 0.f;
    for (int k = 0; k < K; k++) c += s_q[k] * bh[k];
    cb[b] = c;
  }
  for (int h = tid; h < H; h += 256) {
    float acc = 0.f;
    #pragma unroll 4
    for (int k = 0; k < K; k++) acc += s_q[k] * Wh[(size_t)k * H + h];
    wq[b * H + h] = acc;
  }
}

// ---------------------------------------------------------------------------
// Kernel B (fused): single pass over VALID rows of L, online softmax.
// One wave per row-pair (unroll 2, independent reduce chains).
// Lane holds h = lane*4..+4 and 256+lane*4..+4.
// ---------------------------------------------------------------------------
__global__ __launch_bounds__(256) void fused_kernel(
    const float* __restrict__ L, const float* __restrict__ wq,
    const float* __restrict__ cb, const int* __restrict__ len,
    float* __restrict__ energy, float* __restrict__ partials) {
  const int b = blockIdx.x >> 5;
  const int sp = blockIdx.x & (SPL - 1);
  const int lane = threadIdx.x & 63;
  const int wave = threadIdx.x >> 6;
  const int tid = threadIdx.x;
  const int lb = (b == 0) ? T : len[b];

  __shared__ float s_ctx[4][H];
  __shared__ float s_ml[4][2];

  const int h0 = lane * 4;
  float m = -__builtin_huge_valf();
  float lsum = 0.f;
  float4 acc0 = {0.f, 0.f, 0.f, 0.f};
  float4 acc1 = {0.f, 0.f, 0.f, 0.f};

  const int start = sp * RPB + wave * RPW;
  const int end = min(start + RPW, lb);

  if (start < end) {
    const float4 q0 = *(const float4*)(wq + b * H + h0);
    const float4 q1 = *(const float4*)(wq + b * H + 256 + h0);
    const float c = cb[b];
    const float* Lr = L + ((size_t)b * T + start) * H;
    int r = start;
    // main loop: 2 rows per iteration, independent reduce chains
    for (; r + 1 < end; r += 2, Lr += 2 * H) {
      const float4 a0 = *(const float4*)(Lr + h0);
      const float4 a1 = *(const float4*)(Lr + 256 + h0);
      const float4 b0 = *(const float4*)(Lr + H + h0);
      const float4 b1 = *(const float4*)(Lr + H + 256 + h0);
      float d0 = a0.x * q0.x + a0.y * q0.y + a0.z * q0.z + a0.w * q0.w +
                 a1.x * q1.x + a1.y * q1.y + a1.z * q1.z + a1.w * q1.w;
      float d1 = b0.x * q0.x + b0.y * q0.y + b0.z * q0.z + b0.w * q0.w +
                 b1.x * q1.x + b1.y * q1.y + b1.z * q1.z + b1.w * q1.w;
      #pragma unroll
      for (int off = 32; off > 0; off >>= 1) {
        d0 += __shfl_xor(d0, off);
        d1 += __shfl_xor(d1, off);
      }
      const float e0 = d0 + c;
      const float e1 = d1 + c;
      if (lane == 0) {
        energy[b * T + r] = e0;
        energy[b * T + r + 1] = e1;
      }
      const float mn = fmaxf(m, fmaxf(e0, e1));
      const float s = __expf(m - mn);        // ==1 when m unchanged
      const float w0 = __expf(e0 - mn);
      const float w1 = __expf(e1 - mn);
      m = mn;
      lsum = lsum * s + w0 + w1;
      acc0.x = acc0.x * s + w0 * a0.x + w1 * b0.x;
      acc0.y = acc0.y * s + w0 * a0.y + w1 * b0.y;
      acc0.z = acc0.z * s + w0 * a0.z + w1 * b0.z;
      acc0.w = acc0.w * s + w0 * a0.w + w1 * b0.w;
      acc1.x = acc1.x * s + w0 * a1.x + w1 * b1.x;
      acc1.y = acc1.y * s + w0 * a1.y + w1 * b1.y;
      acc1.z = acc1.z * s + w0 * a1.z + w1 * b1.z;
      acc1.w = acc1.w * s + w0 * a1.w + w1 * b1.w;
    }
    // tail row
    if (r < end) {
      const float4 a0 = *(const float4*)(Lr + h0);
      const float4 a1 = *(const float4*)(Lr + 256 + h0);
      float d = a0.x * q0.x + a0.y * q0.y + a0.z * q0.z + a0.w * q0.w +
                a1.x * q1.x + a1.y * q1.y + a1.z * q1.z + a1.w * q1.w;
      #pragma unroll
      for (int off = 32; off > 0; off >>= 1) d += __shfl_xor(d, off);
      const float e = d + c;
      if (lane == 0) energy[b * T + r] = e;
      const float mn = fmaxf(m, e);
      const float s = __expf(m - mn);
      const float w = __expf(e - mn);
      m = mn;
      lsum = lsum * s + w;
      acc0.x = acc0.x * s + w * a0.x;
      acc0.y = acc0.y * s + w * a0.y;
      acc0.z = acc0.z * s + w * a0.z;
      acc0.w = acc0.w * s + w * a0.w;
      acc1.x = acc1.x * s + w * a1.x;
      acc1.y = acc1.y * s + w * a1.y;
      acc1.z = acc1.z * s + w * a1.z;
      acc1.w = acc1.w * s + w * a1.w;
    }
  }

  if (lane == 0) { s_ml[wave][0] = m; s_ml[wave][1] = lsum; }
  *(float4*)&s_ctx[wave][h0] = acc0;
  *(float4*)&s_ctx[wave][256 + h0] = acc1;
  __syncthreads();

  const float M = fmaxf(fmaxf(s_ml[0][0], s_ml[1][0]),
                        fmaxf(s_ml[2][0], s_ml[3][0]));
  float sc[4], ltot = 0.f;
  #pragma unroll
  for (int w = 0; w < 4; w++) {
    sc[w] = (s_ml[w][0] > -1e38f) ? __expf(s_ml[w][0] - M) : 0.f;
    ltot += s_ml[w][1] * sc[w];
  }
  float v0 = 0.f, v1 = 0.f;
  #pragma unroll
  for (int w = 0; w < 4; w++) {
    v0 += s_ctx[w][tid * 2] * sc[w];
    v1 += s_ctx[w][tid * 2 + 1] * sc[w];
  }
  float* part = partials + (size_t)blockIdx.x * PSTRIDE;
  *(float2*)(part + tid * 2) = make_float2(v0, v1);
  if (tid == 0) { part[512] = M; part[513] = ltot; }
}

// ---------------------------------------------------------------------------
// Kernel C: combine SPL split-partials per batch, Wv GEMV, AND write att row.
// ---------------------------------------------------------------------------
__global__ __launch_bounds__(256) void combine_kernel(
    const float* __restrict__ partials, const float* __restrict__ Wv,
    const float* __restrict__ bv, const float* __restrict__ energy,
    const int* __restrict__ len, float* __restrict__ ctx_out,
    float* __restrict__ att) {
  const int b = blockIdx.x;
  const int tid = threadIdx.x;
  __shared__ float s_ml[SPL][2];
  __shared__ float s_ctx[H];

  if (tid < SPL) {
    const float* p = partials + (size_t)(b * SPL + tid) * PSTRIDE;
    s_ml[tid][0] = p[512];
    s_ml[tid][1] = p[513];
  }
  __syncthreads();

  float M = -__builtin_huge_valf();
  #pragma unroll
  for (int sp = 0; sp < SPL; sp++) M = fmaxf(M, s_ml[sp][0]);
  float ltot = 0.f;
  #pragma unroll
  for (int sp = 0; sp < SPL; sp++) {
    const float s = (s_ml[sp][0] > -1e38f) ? __expf(s_ml[sp][0] - M) : 0.f;
    ltot += s_ml[sp][1] * s;
  }
  const float inv = 1.0f / fmaxf(ltot, 1e-12f);

  float v0 = 0.f, v1 = 0.f;
  #pragma unroll 4
  for (int sp = 0; sp < SPL; sp++) {
    const float s = (s_ml[sp][0] > -1e38f) ? __expf(s_ml[sp][0] - M) : 0.f;
    const float* p = partials + (size_t)(b * SPL + sp) * PSTRIDE;
    v0 += p[tid * 2] * s;
    v1 += p[tid * 2 + 1] * s;
  }
  s_ctx[tid * 2] = v0 * inv;
  s_ctx[tid * 2 + 1] = v1 * inv;
  __syncthreads();

  // attention row: att[b,t] = (t < lb) ? exp(e - M) * inv : 0
  const int lb = (b == 0) ? T : len[b];
  #pragma unroll
  for (int i = 0; i < 8; i++) {
    const int t = tid + 256 * i;
    const float e = (t < lb) ? energy[b * T + t] : M;
    att[b * T + t] = (t < lb) ? __expf(e - M) * inv : 0.f;
  }

  if (tid < V) {
    const float* w = Wv + (size_t)tid * H;
    float a = bv[tid];
    #pragma unroll 4
    for (int h = 0; h < H; h += 4) {
      a += w[h] * s_ctx[h] + w[h + 1] * s_ctx[h + 1] +
           w[h + 2] * s_ctx[h + 2] + w[h + 3] * s_ctx[h + 3];
    }
    ctx_out[b * V + tid] = a;
  }
}

extern "C" void kernel_launch(void* const* d_in, const int* in_sizes, int n_in,
                              void* d_out, int out_size, void* d_ws,
                              size_t ws_size, hipStream_t stream) {
  const float* dec = (const float*)d_in[0];   // (B,S)
  const float* L   = (const float*)d_in[1];   // (B,T,H)
  const int*   len = (const int*)d_in[2];     // (B,)
  const float* Ws  = (const float*)d_in[3];   // (K,S)
  const float* bs  = (const float*)d_in[4];   // (K,)
  const float* Wh  = (const float*)d_in[5];   // (K,H)
  const float* bh  = (const float*)d_in[6];   // (K,)
  const float* Wv  = (const float*)d_in[7];   // (V,H)
  const float* bv  = (const float*)d_in[8];   // (V,)

  float* ctx_out = (float*)d_out;             // (B,V)
  float* att_out = (float*)d_out + B * V;     // (B,1,T)

  // workspace layout (floats):
  float* ws = (float*)d_ws;
  float* wq = ws;                               // B*H   = 32768
  float* cb = wq + B * H;                       // B     = 64
  float* energy = cb + B;                       // B*T   = 131072
  float* partials = energy + B * T;             // B*SPL*PSTRIDE = 1056768

  prep_kernel<<<B, 256, 0, stream>>>(dec, Ws, bs, Wh, bh, wq, cb);
  fused_kernel<<<B * SPL, 256, 0, stream>>>(L, wq, cb, len, energy, partials);
  combine_kernel<<<B, 256, 0, stream>>>(partials, Wv, bv, energy, len,
                                        ctx_out, att_out);
}